// Round 1
// baseline (1993.229 us; speedup 1.0000x reference)
//
#include <hip/hip_runtime.h>

namespace {

constexpr int IMG  = 512;
constexpr int K    = 51;
constexpr int PAD  = 25;          // K/2
constexpr int TX   = 32;          // output tile width
constexpr int TY   = 32;          // output tile height
constexpr int G    = 4;           // pixels per thread along x
constexpr int TXG  = TX / G;      // 8 x-groups
constexpr int PW   = TX + K - 1;  // 82 padded cols per tile
constexpr int PWP  = 84;          // row length padded to 16B multiple
constexpr int NSLOT = TY + 1;     // 33-slot circular row buffer
constexpr int NTHREADS = TXG * TY; // 256

__global__ __launch_bounds__(NTHREADS, 1)
void sepconv_kernel(const float* __restrict__ frame0,
                    const float* __restrict__ frame2,
                    const float* __restrict__ V1, const float* __restrict__ H1,
                    const float* __restrict__ V2, const float* __restrict__ H2,
                    float* __restrict__ out)
{
    __shared__ __align__(16) float lds[NSLOT][3][PWP];

    const int tid = threadIdx.x;
    const int xg  = tid % TXG;     // 0..7
    const int yt  = tid / TXG;     // 0..31
    const int x0  = blockIdx.x * TX;
    const int y0  = blockIdx.y * TY;
    const int b   = blockIdx.z;

    const int x = x0 + xg * G;     // first output col of this thread
    const int y = y0 + yt;         // output row of this thread

    // staging role: threads 0..245 each own one (channel, padded-col) of a row
    const int  sc      = tid / PW;         // staging channel
    const int  scol_l  = tid % PW;         // local padded col
    const bool do_stage = (tid < 3 * PW);
    const int  scol    = min(max(x0 + scol_l - PAD, 0), IMG - 1);

    const size_t plane = (size_t)IMG * IMG;

    float acc[3][G];
    #pragma unroll
    for (int c = 0; c < 3; ++c)
        #pragma unroll
        for (int g = 0; g < G; ++g) acc[c][g] = 0.f;

    #pragma unroll 1
    for (int f = 0; f < 2; ++f) {
        const float* __restrict__ frame = f ? frame2 : frame0;
        const float* __restrict__ Vp = (f ? V2 : V1) + (size_t)b * K * plane
                                       + (size_t)y * IMG + x;
        const float* __restrict__ Hp = (f ? H2 : H1) + (size_t)b * K * plane
                                       + (size_t)y * IMG + x;
        const float* __restrict__ fbase =
            frame + (size_t)(b * 3 + sc) * plane + scol;

        // H taps for my G pixels -> registers (h[g][j], fully static-indexed)
        float h[G][K];
        #pragma unroll
        for (int j = 0; j < K; ++j) {
            const float4 hv = *(const float4*)(Hp + (size_t)j * plane);
            h[0][j] = hv.x; h[1][j] = hv.y; h[2][j] = hv.z; h[3][j] = hv.w;
        }

        __syncthreads();   // previous frame's LDS reads done before restaging

        // prologue: stage padded rows 0..TY-1 (local row lr -> slot lr%NSLOT)
        for (int lr = 0; lr < TY; ++lr) {
            if (do_stage) {
                const int srow = min(max(y0 + lr - PAD, 0), IMG - 1);
                lds[lr % NSLOT][sc][scol_l] = fbase[(size_t)srow * IMG];
            }
        }

        #pragma unroll 1
        for (int i = 0; i < K; ++i) {
            __syncthreads();   // staged rows visible; prev-step write ordered

            const float4 vv = *(const float4*)(Vp + (size_t)i * plane);
            const int slot = (yt + i) % NSLOT;
            const float* rowp0 = &lds[slot][0][xg * G];

            #pragma unroll
            for (int c = 0; c < 3; ++c) {
                const float* rowp = rowp0 + c * PWP;
                float r[G] = {0.f, 0.f, 0.f, 0.f};
                // 54 needed floats (t = 0..53), read as 14 x float4
                #pragma unroll
                for (int tc = 0; tc < 14; ++tc) {
                    const float4 p4 = *(const float4*)(rowp + tc * 4);
                    const float pe[4] = {p4.x, p4.y, p4.z, p4.w};
                    #pragma unroll
                    for (int e = 0; e < 4; ++e) {
                        const int t = tc * 4 + e;
                        #pragma unroll
                        for (int g = 0; g < G; ++g) {
                            const int jj = t - g;          // compile-time
                            if (jj >= 0 && jj < K)
                                r[g] = fmaf(pe[e], h[g][jj], r[g]);
                        }
                    }
                }
                acc[c][0] = fmaf(vv.x, r[0], acc[c][0]);
                acc[c][1] = fmaf(vv.y, r[1], acc[c][1]);
                acc[c][2] = fmaf(vv.z, r[2], acc[c][2]);
                acc[c][3] = fmaf(vv.w, r[3], acc[c][3]);
            }

            // stage next padded row (slot (i+TY)%NSLOT is disjoint from all
            // slots read this step; next step's barrier orders write->read)
            const int lr = i + TY;
            if (lr < TY + K - 1 && do_stage) {
                const int srow = min(max(y0 + lr - PAD, 0), IMG - 1);
                lds[lr % NSLOT][sc][scol_l] = fbase[(size_t)srow * IMG];
            }
        }
    }

    #pragma unroll
    for (int c = 0; c < 3; ++c) {
        float4 o;
        o.x = acc[c][0]; o.y = acc[c][1]; o.z = acc[c][2]; o.w = acc[c][3];
        *(float4*)(out + (size_t)(b * 3 + c) * plane + (size_t)y * IMG + x) = o;
    }
}

} // namespace

extern "C" void kernel_launch(void* const* d_in, const int* in_sizes, int n_in,
                              void* d_out, int out_size, void* d_ws, size_t ws_size,
                              hipStream_t stream)
{
    const float* frame0 = (const float*)d_in[0];
    const float* frame2 = (const float*)d_in[1];
    const float* V1 = (const float*)d_in[2];
    const float* H1 = (const float*)d_in[3];
    const float* V2 = (const float*)d_in[4];
    const float* H2 = (const float*)d_in[5];
    float* o = (float*)d_out;

    dim3 grid(IMG / TX, IMG / TY, 2);
    dim3 block(NTHREADS);
    hipLaunchKernelGGL(sepconv_kernel, grid, block, 0, stream,
                       frame0, frame2, V1, H1, V2, H2, o);
}

// Round 2
// 665.792 us; speedup vs baseline: 2.9938x; 2.9938x over previous
//
#include <hip/hip_runtime.h>
#include <stdint.h>

namespace {

typedef _Float16 half2_t __attribute__((ext_vector_type(2)));

template <int N> struct IC { static constexpr int value = N; };

__device__ __forceinline__ float fdot2(uint32_t a, uint32_t b, float c) {
#if __has_builtin(__builtin_amdgcn_fdot2)
  return __builtin_amdgcn_fdot2(__builtin_bit_cast(half2_t, a),
                                __builtin_bit_cast(half2_t, b), c, false);
#else
  float d;
  asm("v_dot2_f32_f16 %0, %1, %2, %3" : "=v"(d) : "v"(a), "v"(b), "v"(c));
  return d;
#endif
}

__device__ __forceinline__ uint32_t pkrtz(float a, float b) {
  return __builtin_bit_cast(uint32_t, __builtin_amdgcn_cvt_pkrtz(a, b));
}

constexpr int IMG = 512, K = 51, PAD = 25;
constexpr int NT = 128;                  // 2 waves; 4 px per lane -> full 512 row
constexpr int PW_PAIRS = 282;            // half2 pairs per channel row (564 cols)
constexpr int NPAIR_TOT = 3 * PW_PAIRS;  // 846
constexpr int CH_DW = 384;               // dwords per channel row (96 x 16B granules)
constexpr int ROW_DW = 3 * CH_DW;        // 1152
constexpr int SLOTS = 8;                 // circular row buffer

// 16B-granule XOR swizzle: kills the 4-way bank-quad aliasing of q, q+8, q+16, q+24
__device__ __forceinline__ int swz(int q) { return q ^ ((q >> 2) & 6); }

__global__ __launch_bounds__(NT, 2)
void sepconv(const float* __restrict__ fr0, const float* __restrict__ fr2,
             const float* __restrict__ V1, const float* __restrict__ H1,
             const float* __restrict__ V2, const float* __restrict__ H2,
             float* __restrict__ out)
{
  __shared__ __align__(16) uint32_t smem[SLOTS * ROW_DW];  // 36864 B

  const int tid = threadIdx.x;
  const int e = tid & 1;            // window-base parity, absorbed into H packing
  const int y = blockIdx.x;         // output row
  const int b = blockIdx.y;         // batch
  const size_t plane = (size_t)IMG * IMG;
  const int xb = 4 * tid;           // first output col of this lane

  // byte offsets of the 8 window b128 reads (lane pairs 2m,2m+1 broadcast)
  int roff[8];
  #pragma unroll
  for (int t = 0; t < 8; ++t) roff[t] = 16 * swz((tid >> 1) + t);

  // ---- staging precompute: 7 half2 pairs per thread per row ----
  const bool k6 = tid < (NPAIR_TOT - 6 * NT);  // tid < 78
  int sdw[7], sg0[7], sg1[7], scb[7];
  #pragma unroll
  for (int k = 0; k < 7; ++k) {
    if (k < 6 || k6) {
      const int P = tid + k * NT;
      const int c = P / PW_PAIRS;
      const int p = P - c * PW_PAIRS;          // pair within channel row
      sdw[k] = c * CH_DW + 4 * swz(p >> 2) + (p & 3);
      sg0[k] = min(max(2 * p - 26, 0), IMG - 1);   // local col -> global, clamped
      sg1[k] = min(max(2 * p - 25, 0), IMG - 1);
      scb[k] = (b * 3 + c) * (int)plane;
    } else { sdw[k] = 0; sg0[k] = 0; sg1[k] = 0; scb[k] = 0; }
  }

  float la[7], lb[7];                 // in-flight staged row (load-early/write-late)
  float acc[3][4];
  #pragma unroll
  for (int c = 0; c < 3; ++c)
    #pragma unroll
    for (int g = 0; g < 4; ++g) acc[c][g] = 0.f;

  #pragma unroll 1
  for (int f = 0; f < 2; ++f) {
    const float* __restrict__ fr = f ? fr2 : fr0;
    const float* __restrict__ Vb = (f ? V2 : V1) + (size_t)b * K * plane
                                   + (size_t)y * IMG + xb;
    const float* __restrict__ Hb = (f ? H2 : H1) + (size_t)b * K * plane
                                   + (size_t)y * IMG + xb;

    // ---- pack per-pixel H taps into per-lane half2, parity-shifted by 2e ----
    // hh[g][u] pairs with window pair u (cols 8*(tid>>1)+2u, +1);
    // tap j0 = 2u - 4e - g - 1 -> hh[g][u] = (h[j0], h[j0+1]), 0 outside [0,50]
    uint32_t hh[4][30];
    #pragma unroll
    for (int g = 0; g < 4; ++g)
      #pragma unroll
      for (int u = 0; u < 30; ++u) hh[g][u] = 0u;

    const float* HbL = Hb;
    auto packH = [&](auto EOFFC) {
      constexpr int EOFF = decltype(EOFFC)::value;
      float prevv[4] = {0.f, 0.f, 0.f, 0.f};
      #pragma unroll
      for (int j = 0; j <= K; ++j) {
        float curv[4] = {0.f, 0.f, 0.f, 0.f};
        if (j < K) *(float4*)curv = *(const float4*)(HbL + (size_t)j * plane);
        #pragma unroll
        for (int g = 0; g < 4; ++g) {
          if (((j + g) & 1) == 0)
            hh[g][((j + g) >> 1) + EOFF] = pkrtz(prevv[g], curv[g]);
          prevv[g] = curv[g];
        }
      }
    };
    if (e == 0) packH(IC<0>{}); else packH(IC<2>{});

    // ---- staging helpers ----
    auto stage_load = [&](int lr) {
      const int gy = min(max(y - PAD + lr, 0), IMG - 1);
      const int rb = gy * IMG;
      #pragma unroll
      for (int k = 0; k < 7; ++k)
        if (k < 6 || k6) {
          la[k] = fr[(size_t)(scb[k] + rb + sg0[k])];
          lb[k] = fr[(size_t)(scb[k] + rb + sg1[k])];
        }
    };
    auto stage_write = [&](int slot) {
      #pragma unroll
      for (int k = 0; k < 7; ++k)
        if (k < 6 || k6)
          smem[slot * ROW_DW + sdw[k]] = pkrtz(la[k], lb[k]);
    };

    __syncthreads();                  // previous frame's reads complete
    #pragma unroll
    for (int lr = 0; lr < 4; ++lr) { stage_load(lr); stage_write(lr); }
    stage_load(4);

    // ---- main K loop: one frame row tap per step ----
    #pragma unroll 1
    for (int s = 0; s < K; ++s) {
      __syncthreads();                // row s visible; prior writes ordered
      const float4 vv = *(const float4*)(Vb + (size_t)s * plane);
      const float vs[4] = {vv.x, vv.y, vv.z, vv.w};
      const int rbase = (s & 7) * (ROW_DW * 4);

      #pragma unroll
      for (int c = 0; c < 3; ++c) {
        uint32_t w[32];
        const char* base = (const char*)smem + rbase + c * (CH_DW * 4);
        #pragma unroll
        for (int t = 0; t < 8; ++t)
          *(uint4*)&w[4 * t] = *(const uint4*)(base + roff[t]);

        float ra[4] = {0.f, 0.f, 0.f, 0.f}, rb2[4] = {0.f, 0.f, 0.f, 0.f};
        #pragma unroll
        for (int u = 0; u < 30; ++u) {
          #pragma unroll
          for (int g = 0; g < 4; ++g) {
            if (u & 1) rb2[g] = fdot2(w[u], hh[g][u], rb2[g]);
            else       ra[g] = fdot2(w[u], hh[g][u], ra[g]);
          }
        }
        #pragma unroll
        for (int g = 0; g < 4; ++g)
          acc[c][g] = fmaf(vs[g], ra[g] + rb2[g], acc[c][g]);
      }

      // write row s+4 (loaded at step s-1), issue loads for row s+5
      if (s + 4 <= K - 1) stage_write((s + 4) & 7);
      if (s + 5 <= K - 1) stage_load(s + 5);
    }
  }

  #pragma unroll
  for (int c = 0; c < 3; ++c) {
    float4 o;
    o.x = acc[c][0]; o.y = acc[c][1]; o.z = acc[c][2]; o.w = acc[c][3];
    *(float4*)(out + ((size_t)(b * 3 + c) * IMG + y) * IMG + xb) = o;
  }
}

} // namespace

extern "C" void kernel_launch(void* const* d_in, const int* in_sizes, int n_in,
                              void* d_out, int out_size, void* d_ws, size_t ws_size,
                              hipStream_t stream)
{
  const float* frame0 = (const float*)d_in[0];
  const float* frame2 = (const float*)d_in[1];
  const float* V1 = (const float*)d_in[2];
  const float* H1 = (const float*)d_in[3];
  const float* V2 = (const float*)d_in[4];
  const float* H2 = (const float*)d_in[5];
  float* o = (float*)d_out;

  dim3 grid(IMG, 2);
  dim3 block(NT);
  hipLaunchKernelGGL(sepconv, grid, block, 0, stream,
                     frame0, frame2, V1, H1, V2, H2, o);
}

// Round 3
// 267.178 us; speedup vs baseline: 7.4603x; 2.4919x over previous
//
#include <hip/hip_runtime.h>
#include <stdint.h>

namespace {

typedef _Float16 half2_t __attribute__((ext_vector_type(2)));

template <int N> struct IC { static constexpr int value = N; };

__device__ __forceinline__ float fdot2(uint32_t a, uint32_t b, float c) {
#if __has_builtin(__builtin_amdgcn_fdot2)
  return __builtin_amdgcn_fdot2(__builtin_bit_cast(half2_t, a),
                                __builtin_bit_cast(half2_t, b), c, false);
#else
  float d;
  asm("v_dot2_f32_f16 %0, %1, %2, %3" : "=v"(d) : "v"(a), "v"(b), "v"(c));
  return d;
#endif
}

__device__ __forceinline__ uint32_t pkrtz(float a, float b) {
  return __builtin_bit_cast(uint32_t, __builtin_amdgcn_cvt_pkrtz(a, b));
}

constexpr int IMG = 512, K = 51, PAD = 25;
constexpr int NT = 128;                  // 2 waves; 4 px per lane -> full 512 row
constexpr int PW_PAIRS = 282;            // half2 pairs per channel row (564 cols)
constexpr int NPAIR_TOT = 3 * PW_PAIRS;  // 846
constexpr int CH_DW = 384;               // dwords per channel row (96 x 16B granules)
constexpr int ROW_DW = 3 * CH_DW;        // 1152
constexpr int SLOTS = 8;                 // circular row buffer

// 16B-granule XOR swizzle: kills the 4-way bank-quad aliasing of q, q+8, q+16, q+24
__device__ __forceinline__ int swz(int q) { return q ^ ((q >> 2) & 6); }

__global__ __launch_bounds__(NT)
__attribute__((amdgpu_waves_per_eu(2, 2)))
void sepconv(const float* __restrict__ fr0, const float* __restrict__ fr2,
             const float* __restrict__ V1, const float* __restrict__ H1,
             const float* __restrict__ V2, const float* __restrict__ H2,
             float* __restrict__ out)
{
  __shared__ __align__(16) uint32_t smem[SLOTS * ROW_DW];  // 36864 B

  const int tid = threadIdx.x;
  const int e = tid & 1;            // window-base parity, absorbed into H packing
  const int y = blockIdx.x;         // output row
  const int b = blockIdx.y;         // batch
  const size_t plane = (size_t)IMG * IMG;
  const int xb = 4 * tid;           // first output col of this lane

  // byte offsets of the 8 window b128 reads (lane pairs 2m,2m+1 broadcast)
  int roff[8];
  #pragma unroll
  for (int t = 0; t < 8; ++t) roff[t] = 16 * swz((tid >> 1) + t);

  // ---- staging precompute: 7 half2 pairs per thread per row ----
  const bool k6 = tid < (NPAIR_TOT - 6 * NT);  // tid < 78
  int sdw[7], soff0[7], soff1[7];
  #pragma unroll
  for (int k = 0; k < 7; ++k) {
    if (k < 6 || k6) {
      const int P = tid + k * NT;
      const int c = P / PW_PAIRS;
      const int p = P - c * PW_PAIRS;          // pair within channel row
      sdw[k] = c * CH_DW + 4 * swz(p >> 2) + (p & 3);
      const int cb = (b * 3 + c) * (int)plane;
      soff0[k] = cb + min(max(2 * p - 26, 0), IMG - 1);
      soff1[k] = cb + min(max(2 * p - 25, 0), IMG - 1);
    } else { sdw[k] = 0; soff0[k] = 0; soff1[k] = 0; }
  }

  float la[7], lb[7];                 // single in-flight staged row
  float acc[3][4];
  #pragma unroll
  for (int c = 0; c < 3; ++c)
    #pragma unroll
    for (int g = 0; g < 4; ++g) acc[c][g] = 0.f;

  #pragma unroll 1
  for (int f = 0; f < 2; ++f) {
    const float* __restrict__ fr = f ? fr2 : fr0;
    const float* __restrict__ Vb = (f ? V2 : V1) + (size_t)b * K * plane
                                   + (size_t)y * IMG + xb;
    const float* __restrict__ Hb = (f ? H2 : H1) + (size_t)b * K * plane
                                   + (size_t)y * IMG + xb;

    // V[0] prefetch (consumed at step 0)
    float4 vcur = *(const float4*)(Vb);

    // ---- pack per-pixel H taps into per-lane half2, parity-shifted by 2e ----
    // hh[g][u] pairs with window pair u (cols 8*(tid>>1)+2u, +1);
    // tap j0 = 2u - 4e - g - 1 -> hh[g][u] = (h[j0], h[j0+1]), 0 outside [0,50]
    uint32_t hh[4][30];
    #pragma unroll
    for (int g = 0; g < 4; ++g)
      #pragma unroll
      for (int u = 0; u < 30; ++u) hh[g][u] = 0u;

    auto packH = [&](auto EOFFC) {
      constexpr int EOFF = decltype(EOFFC)::value;
      float prevv[4] = {0.f, 0.f, 0.f, 0.f};
      #pragma unroll
      for (int j = 0; j <= K; ++j) {
        float curv[4] = {0.f, 0.f, 0.f, 0.f};
        if (j < K) *(float4*)curv = *(const float4*)(Hb + (size_t)j * plane);
        #pragma unroll
        for (int g = 0; g < 4; ++g) {
          if (((j + g) & 1) == 0)
            hh[g][((j + g) >> 1) + EOFF] = pkrtz(prevv[g], curv[g]);
          prevv[g] = curv[g];
        }
      }
    };
    if (e == 0) packH(IC<0>{}); else packH(IC<2>{});

    auto stage_load = [&](int lr) {
      const int gy = min(max(y - PAD + lr, 0), IMG - 1);
      const int rb = gy * IMG;
      #pragma unroll
      for (int k = 0; k < 7; ++k)
        if (k < 6 || k6) {
          la[k] = fr[(size_t)(soff0[k] + rb)];
          lb[k] = fr[(size_t)(soff1[k] + rb)];
        }
    };
    auto stage_write = [&](int slot) {
      #pragma unroll
      for (int k = 0; k < 7; ++k)
        if (k < 6 || k6)
          smem[slot * ROW_DW + sdw[k]] = pkrtz(la[k], lb[k]);
    };

    // ---- prologue: rows 0..2 staged directly, row 3 left in la/lb ----
    __syncthreads();                  // previous frame's reads complete
    #pragma unroll 1
    for (int lr = 0; lr < 3; ++lr) { stage_load(lr); stage_write(lr & 7); }
    stage_load(3);

    // ---- main K loop: one row tap per step ----
    #pragma unroll 1
    for (int s = 0; s < K; ++s) {
      __syncthreads();                // row s visible; prior writes ordered

      // 1) write row s+3 (loaded a full step ago -> latency already covered)
      if (s + 3 <= K - 1) stage_write((s + 3) & 7);
      // 2) issue loads for row s+4 (drained ~free at barrier of step s+1)
      if (s + 4 <= K - 1) stage_load(s + 4);
      // 3) issue V prefetch for step s+1
      float4 vnext;
      if (s + 1 < K) vnext = *(const float4*)(Vb + (size_t)(s + 1) * plane);

      const float vs[4] = {vcur.x, vcur.y, vcur.z, vcur.w};
      const int rbase = (s & 7) * (ROW_DW * 4);

      #pragma unroll
      for (int c = 0; c < 3; ++c) {
        const char* base = (const char*)smem + rbase + c * (CH_DW * 4);
        float ra[4] = {0.f, 0.f, 0.f, 0.f}, rb2[4] = {0.f, 0.f, 0.f, 0.f};
        #pragma unroll
        for (int t = 0; t < 8; ++t) {
          const uint4 w4 = *(const uint4*)(base + roff[t]);
          const uint32_t wd[4] = {w4.x, w4.y, w4.z, w4.w};
          #pragma unroll
          for (int eI = 0; eI < 4; ++eI) {
            const int u = 4 * t + eI;
            if (u < 30) {
              #pragma unroll
              for (int g = 0; g < 4; ++g) {
                if (u & 1) rb2[g] = fdot2(wd[eI], hh[g][u], rb2[g]);
                else       ra[g] = fdot2(wd[eI], hh[g][u], ra[g]);
              }
            }
          }
        }
        #pragma unroll
        for (int g = 0; g < 4; ++g)
          acc[c][g] = fmaf(vs[g], ra[g] + rb2[g], acc[c][g]);
      }
      vcur = vnext;
    }
  }

  #pragma unroll
  for (int c = 0; c < 3; ++c) {
    float4 o;
    o.x = acc[c][0]; o.y = acc[c][1]; o.z = acc[c][2]; o.w = acc[c][3];
    *(float4*)(out + ((size_t)(b * 3 + c) * IMG + y) * IMG + xb) = o;
  }
}

} // namespace

extern "C" void kernel_launch(void* const* d_in, const int* in_sizes, int n_in,
                              void* d_out, int out_size, void* d_ws, size_t ws_size,
                              hipStream_t stream)
{
  const float* frame0 = (const float*)d_in[0];
  const float* frame2 = (const float*)d_in[1];
  const float* V1 = (const float*)d_in[2];
  const float* H1 = (const float*)d_in[3];
  const float* V2 = (const float*)d_in[4];
  const float* H2 = (const float*)d_in[5];
  float* o = (float*)d_out;

  dim3 grid(IMG, 2);
  dim3 block(NT);
  hipLaunchKernelGGL(sepconv, grid, block, 0, stream,
                     frame0, frame2, V1, H1, V2, H2, o);
}